// Round 4
// baseline (223.834 us; speedup 1.0000x reference)
//
#include <hip/hip_runtime.h>
#include <hip/hip_fp16.h>

// AdultConnectomeNetwork: 3 layers of  x = A @ (W @ x) + bias
// A and W share the same sorted-COO pattern (rows sorted, cols random).
// N=50000, NNZ=800000, B=64, L=3.
//
// R3: the SpMM was issuing 24 vmem instructions per 8 edges (8 col + 8 val
// same-address-per-group loads + 8 gathers). Metadata loads cost as much
// TA/issue as the gathers. Fix: pack (col,val) into uint2 arrays once per
// call; each block's 16 rows own a CONTIGUOUS edge slab (rows sorted), so
// the block stages its slab into LDS with coalesced loads and groups read
// edge data via broadcast ds_read_b64. Vmem per 8 edges: 24 -> 8 (gathers
// only). x stays fp16 (128B row = 1 line per gather), fp32 accumulate.

#define EDGE_BATCH 8
#define ROWS_PER_BLOCK 16
#define SEDGE_CAP 2048   // edges; 16 rows ~ Poisson(256) total, 2048 is >> safe

__global__ void build_row_ptr_kernel(const int* __restrict__ rows, int nnz,
                                     int n, int* __restrict__ row_ptr) {
    int r = blockIdx.x * blockDim.x + threadIdx.x;
    if (r > n) return;
    int lo = 0, hi = nnz;
    while (lo < hi) {
        int mid = (lo + hi) >> 1;
        if (rows[mid] < r) lo = mid + 1; else hi = mid;
    }
    row_ptr[r] = lo;
}

// Pack (col, val) pairs for both matrices in one pass.
__global__ void pack_edges_kernel(const int* __restrict__ cols,
                                  const float* __restrict__ wv,
                                  const float* __restrict__ av,
                                  uint2* __restrict__ pw,
                                  uint2* __restrict__ pa, int nnz) {
    int i = blockIdx.x * blockDim.x + threadIdx.x;
    if (i >= nnz) return;
    unsigned int c = (unsigned int)cols[i];
    uint2 w; w.x = c; w.y = __float_as_uint(wv[i]);
    uint2 a; a.x = c; a.y = __float_as_uint(av[i]);
    pw[i] = w;
    pa[i] = a;
}

// fp32 (N*64) -> fp16 (N*64); one thread per 4 elements.
__global__ void f32_to_f16_kernel(const float4* __restrict__ in,
                                  uint2* __restrict__ out, int n4) {
    int i = blockIdx.x * blockDim.x + threadIdx.x;
    if (i >= n4) return;
    float4 v = in[i];
    __half2 h0 = __floats2half2_rn(v.x, v.y);
    __half2 h1 = __floats2half2_rn(v.z, v.w);
    uint2 r;
    r.x = *(unsigned int*)&h0;
    r.y = *(unsigned int*)&h1;
    out[i] = r;
}

// y[r,:] = sum_e val[e] * x16[col[e],:]  (+bias[r]); x16 is fp16.
// Block = 256 threads = 16 groups of 16 lanes; group g owns row r0+g.
// Lane l owns columns [4l, 4l+4) as one uint2 (4 halves).
template <bool ADD_BIAS, bool OUT_F32>
__global__ void spmm_f16_lds_kernel(const uint2* __restrict__ edges,  // packed (col,val)
                                    const int* __restrict__ row_ptr,
                                    const uint2* __restrict__ xin,    // [n*16] fp16x4
                                    const float* __restrict__ bias,
                                    uint2* __restrict__ yout16,       // [n*16] fp16x4
                                    float4* __restrict__ yout32,      // [n*16] fp32x4
                                    int n) {
    __shared__ uint2 sedge[SEDGE_CAP];
    __shared__ int srp[ROWS_PER_BLOCK + 1];

    const int r0 = blockIdx.x * ROWS_PER_BLOCK;
    const int tid = threadIdx.x;

    if (tid <= ROWS_PER_BLOCK) {
        int r = r0 + tid;
        srp[tid] = row_ptr[r > n ? n : r];
    }
    __syncthreads();

    const int ebase = srp[0];
    const int ecount = srp[ROWS_PER_BLOCK] - ebase;
    const bool fast = (ecount <= SEDGE_CAP);

    if (fast) {
        for (int i = tid; i < ecount; i += 256) sedge[i] = edges[ebase + i];
    }
    __syncthreads();

    const int g = tid >> 4;
    const int lane = tid & 15;
    const int row = r0 + g;
    if (row >= n) return;

    const int ls = srp[g] - ebase;       // local edge range of this row
    const int le = srp[g + 1] - ebase;

    float4 acc = make_float4(0.f, 0.f, 0.f, 0.f);

    for (int e = ls; e < le; e += EDGE_BATCH) {
        int   c[EDGE_BATCH];
        float v[EDGE_BATCH];
#pragma unroll
        for (int j = 0; j < EDGE_BATCH; ++j) {
            const int idx = e + j;
            const bool ok = idx < le;
            const int sidx = ok ? idx : ls;           // harmless in-range read
            const uint2 ed = fast ? sedge[sidx] : edges[ebase + sidx];
            c[j] = ok ? (int)ed.x : 0;
            v[j] = ok ? __uint_as_float(ed.y) : 0.f;  // masked edge: v=0, x[0] line is hot
        }
        uint2 raw[EDGE_BATCH];
#pragma unroll
        for (int j = 0; j < EDGE_BATCH; ++j) {
            raw[j] = xin[c[j] * 16 + lane];           // 8B/lane, 128B/row, 1 line
        }
#pragma unroll
        for (int j = 0; j < EDGE_BATCH; ++j) {
            const __half2 h0 = *(const __half2*)&raw[j].x;
            const __half2 h1 = *(const __half2*)&raw[j].y;
            const float2 f0 = __half22float2(h0);
            const float2 f1 = __half22float2(h1);
            acc.x += v[j] * f0.x;
            acc.y += v[j] * f0.y;
            acc.z += v[j] * f1.x;
            acc.w += v[j] * f1.y;
        }
    }

    if (ADD_BIAS) {
        const float b = bias[row];
        acc.x += b; acc.y += b; acc.z += b; acc.w += b;
    }

    if (OUT_F32) {
        yout32[row * 16 + lane] = acc;
    } else {
        __half2 h0 = __floats2half2_rn(acc.x, acc.y);
        __half2 h1 = __floats2half2_rn(acc.z, acc.w);
        uint2 r;
        r.x = *(unsigned int*)&h0;
        r.y = *(unsigned int*)&h1;
        yout16[row * 16 + lane] = r;
    }
}

extern "C" void kernel_launch(void* const* d_in, const int* in_sizes, int n_in,
                              void* d_out, int out_size, void* d_ws, size_t ws_size,
                              hipStream_t stream) {
    const float* x_in     = (const float*)d_in[0];  // (N, 64)
    const float* adj_vals = (const float*)d_in[1];  // (NNZ,)
    const float* w_vals   = (const float*)d_in[2];  // (NNZ,)
    const float* bias     = (const float*)d_in[3];  // (N,)
    const int*   rows     = (const int*)d_in[4];    // (NNZ,) sorted
    const int*   cols     = (const int*)d_in[5];    // (NNZ,)
    // d_in[6] = n_layers (device scalar); structurally 3.

    const int N   = in_sizes[3];
    const int NNZ = in_sizes[1];

    // Workspace: row_ptr | xh | yh | pw | pa
    char* ws = (char*)d_ws;
    int* row_ptr = (int*)ws;
    size_t off = ((size_t)(N + 1) * sizeof(int) + 255) & ~(size_t)255;
    uint2* xh = (uint2*)(ws + off);  off += (size_t)N * 16 * 8;
    uint2* yh = (uint2*)(ws + off);  off += (size_t)N * 16 * 8;
    uint2* pw = (uint2*)(ws + off);  off += (size_t)NNZ * 8;
    uint2* pa = (uint2*)(ws + off);

    // 1) CSR row pointers
    {
        int threads = 256;
        int blocks = (N + 1 + threads - 1) / threads;
        build_row_ptr_kernel<<<blocks, threads, 0, stream>>>(rows, NNZ, N, row_ptr);
    }
    // 2) pack (col,val) for W and A
    {
        int threads = 256;
        int blocks = (NNZ + threads - 1) / threads;
        pack_edges_kernel<<<blocks, threads, 0, stream>>>(cols, w_vals, adj_vals, pw, pa, NNZ);
    }
    // 3) input fp32 -> fp16
    {
        int n4 = N * 16;
        int threads = 256;
        int blocks = (n4 + threads - 1) / threads;
        f32_to_f16_kernel<<<blocks, threads, 0, stream>>>((const float4*)x_in, xh, n4);
    }

    const int threads = 256;
    const int blocks = (N + ROWS_PER_BLOCK - 1) / ROWS_PER_BLOCK;
    float4* out32 = (float4*)d_out;

    // layer 1: yh = W@xh ; xh = A@yh + b
    spmm_f16_lds_kernel<false, false><<<blocks, threads, 0, stream>>>(pw, row_ptr, xh, nullptr, yh, nullptr, N);
    spmm_f16_lds_kernel<true,  false><<<blocks, threads, 0, stream>>>(pa, row_ptr, yh, bias, xh, nullptr, N);
    // layer 2
    spmm_f16_lds_kernel<false, false><<<blocks, threads, 0, stream>>>(pw, row_ptr, xh, nullptr, yh, nullptr, N);
    spmm_f16_lds_kernel<true,  false><<<blocks, threads, 0, stream>>>(pa, row_ptr, yh, bias, xh, nullptr, N);
    // layer 3: last SpMM writes fp32 to d_out
    spmm_f16_lds_kernel<false, false><<<blocks, threads, 0, stream>>>(pw, row_ptr, xh, nullptr, yh, nullptr, N);
    spmm_f16_lds_kernel<true,  true ><<<blocks, threads, 0, stream>>>(pa, row_ptr, yh, bias, nullptr, out32, N);
}